// Round 5
// baseline (82.698 us; speedup 1.0000x reference)
//
#include <hip/hip_runtime.h>
#include <hip/hip_bf16.h>

// PairRE scoring: out[b,n] = -|| t_hat[n]*rt[b] - h_hat[b]*rh[b] ||_2
// B=512, N=2048, E=256.
//
// x(b,n) = dot([T^2 | T]_n , [rt^2 | -2*rt*Hh]_b) + c_b,
//   T = t/||t||, Hh = (h/||h||)*rh, c_b = ||Hh_b||^2.
//
// R5: SINGLE dispatch, no workspace, no grid sync.
// Block = 32(b) x 64(n), grid 512 (2 blocks/CU).
//  phase A: block preps its 32 A-rows (bf16 [rt^2 | -2*rt*Hh]) + c_b into LDS.
//  phase B: per wave, two-pass over its 32 tail rows loaded DIRECTLY in
//   B-fragment layout (lane=ml row, q=k-sub): pass1 = squared-sums ->
//   shfl_xor(16,32) -> inv; pass2 = reload (cache-hot), scale, cvt bf16,
//   4 MFMAs/step (sq-region + lin-region from the same load; k-order free).
// Verified MFMA layouts from R1/R4: mfma(a=A(b-rows), b=T(n-rows)),
//   D: col(lane&15)=n, row((lane>>4)*4+reg)=b.

#define B_DIM 512
#define N_DIM 2048
#define E_DIM 256
#define LDA   520     // LDS row stride (ushorts): 1040B -> 2-way alias (free)

typedef __attribute__((ext_vector_type(8))) __bf16 bf16x8;
typedef __attribute__((ext_vector_type(4))) float f32x4;

__device__ inline ushort f2bf(float x) {
    __hip_bfloat16 h = __float2bfloat16(x);   // RNE
    union { __hip_bfloat16 b; ushort u; } cv; cv.b = h; return cv.u;
}

__device__ inline float wave_sum(float v) {
#pragma unroll
    for (int m = 1; m < 64; m <<= 1) v += __shfl_xor(v, m, 64);
    return v;
}

__global__ __launch_bounds__(256, 2) void pairre_one(
        const float* __restrict__ head, const float* __restrict__ tail,
        const float* __restrict__ rel,  const int* __restrict__ rid,
        float* __restrict__ out) {
    __shared__ ushort Alds[32 * LDA];
    __shared__ float cb_lds[32];

    const int tid = threadIdx.x, lane = tid & 63, wv = tid >> 6;
    const int ml = lane & 15, q = lane >> 4;
    const int bid = blockIdx.x;
    const int p_n = bid & 31, b_super = bid >> 5;   // consecutive ids vary p_n
                                                    // -> T-sharers on one XCD

    // ---- phase A: 32 A-rows -> LDS bf16 row-major [rt^2 (256) | -2*rt*Hh (256)]
#pragma unroll
    for (int j = 0; j < 8; ++j) {
        const int rr = wv * 8 + j;
        const int b = b_super * 32 + rr;
        const int id = rid[b];
        const float4 h4  = *(const float4*)(head + (size_t)b * E_DIM + lane * 4);
        const float4 rh4 = *(const float4*)(rel + (size_t)id * 512 + lane * 4);
        const float4 rt4 = *(const float4*)(rel + (size_t)id * 512 + E_DIM + lane * 4);
        const float s1 = wave_sum(h4.x*h4.x + h4.y*h4.y + h4.z*h4.z + h4.w*h4.w);
        const float inv = 1.0f / fmaxf(sqrtf(s1), 1e-12f);
        const float p0 = h4.x*inv*rh4.x, p1 = h4.y*inv*rh4.y,
                    p2 = h4.z*inv*rh4.z, p3 = h4.w*inv*rh4.w;
        const float s2 = wave_sum(p0*p0 + p1*p1 + p2*p2 + p3*p3);
        if (lane == 0) cb_lds[rr] = s2;
        const ushort4 usq = { f2bf(rt4.x*rt4.x), f2bf(rt4.y*rt4.y),
                              f2bf(rt4.z*rt4.z), f2bf(rt4.w*rt4.w) };
        const ushort4 uli = { f2bf(-2.f*rt4.x*p0), f2bf(-2.f*rt4.y*p1),
                              f2bf(-2.f*rt4.z*p2), f2bf(-2.f*rt4.w*p3) };
        *(ushort4*)&Alds[rr * LDA + lane * 4] = usq;            // 8B, conflict-free
        *(ushort4*)&Alds[rr * LDA + E_DIM + lane * 4] = uli;
    }
    __syncthreads();

    // ---- pass 1: tail row norms, loads already in B-frag layout ----
    const int gT0 = p_n * 4 + (wv >> 1) * 2;
    const float* t0 = tail + (size_t)(gT0 * 16 + ml) * E_DIM + q * 8;
    const float* t1 = t0 + 16 * E_DIM;
    float a0 = 0.f, a1 = 0.f;
#pragma unroll
    for (int s = 0; s < 8; ++s) {
        const float4 x0 = *(const float4*)(t0 + s * 32);
        const float4 x1 = *(const float4*)(t0 + s * 32 + 4);
        const float4 y0 = *(const float4*)(t1 + s * 32);
        const float4 y1 = *(const float4*)(t1 + s * 32 + 4);
        a0 += x0.x*x0.x + x0.y*x0.y + x0.z*x0.z + x0.w*x0.w
            + x1.x*x1.x + x1.y*x1.y + x1.z*x1.z + x1.w*x1.w;
        a1 += y0.x*y0.x + y0.y*y0.y + y0.z*y0.z + y0.w*y0.w
            + y1.x*y1.x + y1.y*y1.y + y1.z*y1.z + y1.w*y1.w;
    }
    // combine the 4 lanes (q=0..3) holding each row
    a0 += __shfl_xor(a0, 16, 64); a0 += __shfl_xor(a0, 32, 64);
    a1 += __shfl_xor(a1, 16, 64); a1 += __shfl_xor(a1, 32, 64);
    const float inv0 = 1.0f / fmaxf(sqrtf(a0), 1e-12f);
    const float inv1 = 1.0f / fmaxf(sqrtf(a1), 1e-12f);

    // ---- pass 2: reload (cache-hot), scale+cvt, 4 MFMAs per step ----
    const ushort* Arow = &Alds[((wv & 1) * 16 + ml) * LDA];
    f32x4 acc0 = {0.f, 0.f, 0.f, 0.f}, acc1 = {0.f, 0.f, 0.f, 0.f};
#pragma unroll
    for (int s = 0; s < 8; ++s) {
        const float4 x0 = *(const float4*)(t0 + s * 32);
        const float4 x1 = *(const float4*)(t0 + s * 32 + 4);
        const float4 y0 = *(const float4*)(t1 + s * 32);
        const float4 y1 = *(const float4*)(t1 + s * 32 + 4);
        const float v0[8] = { x0.x*inv0, x0.y*inv0, x0.z*inv0, x0.w*inv0,
                              x1.x*inv0, x1.y*inv0, x1.z*inv0, x1.w*inv0 };
        const float v1[8] = { y0.x*inv1, y0.y*inv1, y0.z*inv1, y0.w*inv1,
                              y1.x*inv1, y1.y*inv1, y1.z*inv1, y1.w*inv1 };
        union { ushort u[8]; bf16x8 v; } sq0, li0, sq1, li1;
#pragma unroll
        for (int j = 0; j < 8; ++j) {
            sq0.u[j] = f2bf(v0[j] * v0[j]);  li0.u[j] = f2bf(v0[j]);
            sq1.u[j] = f2bf(v1[j] * v1[j]);  li1.u[j] = f2bf(v1[j]);
        }
        const bf16x8 a_lo = *(const bf16x8*)&Arow[s * 32 + q * 8];          // k<256
        const bf16x8 a_hi = *(const bf16x8*)&Arow[E_DIM + s * 32 + q * 8];  // k>=256
        acc0 = __builtin_amdgcn_mfma_f32_16x16x32_bf16(a_lo, sq0.v, acc0, 0, 0, 0);
        acc0 = __builtin_amdgcn_mfma_f32_16x16x32_bf16(a_hi, li0.v, acc0, 0, 0, 0);
        acc1 = __builtin_amdgcn_mfma_f32_16x16x32_bf16(a_lo, sq1.v, acc1, 0, 0, 0);
        acc1 = __builtin_amdgcn_mfma_f32_16x16x32_bf16(a_hi, li1.v, acc1, 0, 0, 0);
    }

    // ---- epilogue ----
    const int n0 = gT0 * 16;
#pragma unroll
    for (int r = 0; r < 4; ++r) {
        const int rloc = (wv & 1) * 16 + q * 4 + r;
        const int b = b_super * 32 + rloc;
        const float cb = cb_lds[rloc];
        out[(size_t)b * N_DIM + n0 + ml]      = -sqrtf(fmaxf(acc0[r] + cb, 0.f));
        out[(size_t)b * N_DIM + n0 + 16 + ml] = -sqrtf(fmaxf(acc1[r] + cb, 0.f));
    }
}

extern "C" void kernel_launch(void* const* d_in, const int* in_sizes, int n_in,
                              void* d_out, int out_size, void* d_ws, size_t ws_size,
                              hipStream_t stream) {
    const float* head = (const float*)d_in[0];
    const float* tail = (const float*)d_in[1];
    const float* rel  = (const float*)d_in[2];
    const int*   rid  = (const int*)d_in[3];
    float* out = (float*)d_out;
    (void)d_ws; (void)ws_size;

    pairre_one<<<512, 256, 0, stream>>>(head, tail, rel, rid, out);
}